// Round 1
// baseline (1106.399 us; speedup 1.0000x reference)
//
#include <hip/hip_runtime.h>

// Problem constants (from reference)
#define N_DEP    32
#define N_INDEP  64
#define N_INTER  16
#define BATCH    65536
#define K_JACOBI 10      // Jacobi sweeps; worst-case contraction ~0.27/sweep
#define BLOCK    128     // threads per block == samples per block (2 waves)

// LDS budget: params 22,784 B + X tile 32,768 B + Z tile 8,192 B = 63,744 B < 64 KiB.
// X/Z tiles use rotation swizzle (chunk' = (chunk + row) & mask) for conflict-free
// float4 reads without padding.

__global__ __launch_bounds__(BLOCK) void clefo_solve(
    const float* __restrict__ Xg, const float* __restrict__ Zg,
    const float* __restrict__ Ug, const float* __restrict__ Bg,
    const float* __restrict__ Tg, const float* __restrict__ Gg,
    const float* __restrict__ Lg, float* __restrict__ Yg)
{
    __shared__ __align__(16) float sB[N_DEP][N_INDEP];   // 2048 f
    __shared__ __align__(16) float sL[N_DEP][N_INDEP];   // 2048 f
    __shared__ __align__(16) float sT[N_DEP][N_INTER];   // 512 f
    __shared__ __align__(16) float sG[N_DEP][N_DEP];     // 1024 f (diag zeroed)
    __shared__ float sU[N_DEP];
    __shared__ float sGd[N_DEP];
    __shared__ __align__(16) float sX[BLOCK][N_INDEP];   // 8192 f, swizzled
    __shared__ __align__(16) float sZ[BLOCK][N_INTER];   // 2048 f, swizzled

    const int tid = threadIdx.x;
    const size_t blockBase = (size_t)blockIdx.x * BLOCK;

    // ---- stage parameters (coalesced, small) ----
    {
        float* pB = &sB[0][0]; float* pL = &sL[0][0];
        for (int i = tid; i < N_DEP * N_INDEP; i += BLOCK) { pB[i] = Bg[i]; pL[i] = Lg[i]; }
        float* pG = &sG[0][0];
        for (int i = tid; i < N_DEP * N_DEP; i += BLOCK) pG[i] = Gg[i];
        float* pT = &sT[0][0];
        for (int i = tid; i < N_DEP * N_INTER; i += BLOCK) pT[i] = Tg[i];
        if (tid < N_DEP) sU[tid] = Ug[tid];
    }
    // ---- stage X/Z tiles coalesced with rotation swizzle ----
    {
        const float4* Xv = (const float4*)(Xg + blockBase * N_INDEP);
        for (int idx = tid; idx < BLOCK * (N_INDEP / 4); idx += BLOCK) {
            float4 v = Xv[idx];
            int s = idx >> 4, c = idx & 15;
            *(float4*)&sX[s][((c + s) & 15) * 4] = v;
        }
        const float4* Zv = (const float4*)(Zg + blockBase * N_INTER);
        for (int idx = tid; idx < BLOCK * (N_INTER / 4); idx += BLOCK) {
            float4 v = Zv[idx];
            int s = idx >> 2, c = idx & 3;
            *(float4*)&sZ[s][((c + s) & 3) * 4] = v;
        }
    }
    __syncthreads();
    if (tid < N_DEP) sGd[tid] = sG[tid][tid];
    __syncthreads();
    if (tid < N_DEP) sG[tid][tid] = 0.0f;   // zero diagonal for Jacobi off-diag matvec
    __syncthreads();

    // ---- prologue: r = U + B x + T z ; lam = L x ----
    float r[N_DEP], lam[N_DEP];
#pragma unroll
    for (int i = 0; i < N_DEP; i++) { r[i] = sU[i]; lam[i] = 0.0f; }

    for (int j4 = 0; j4 < N_INDEP / 4; j4++) {        // runtime loop, small code
        float4 x = *(const float4*)&sX[tid][((j4 + tid) & 15) * 4];
#pragma unroll
        for (int i = 0; i < N_DEP; i++) {
            float4 b = *(const float4*)&sB[i][j4 * 4];
            float4 l = *(const float4*)&sL[i][j4 * 4];
            r[i]   += b.x * x.x + b.y * x.y + b.z * x.z + b.w * x.w;
            lam[i] += l.x * x.x + l.y * x.y + l.z * x.z + l.w * x.w;
        }
    }
    for (int j4 = 0; j4 < N_INTER / 4; j4++) {
        float4 z = *(const float4*)&sZ[tid][((j4 + tid) & 3) * 4];
#pragma unroll
        for (int i = 0; i < N_DEP; i++) {
            float4 t = *(const float4*)&sT[i][j4 * 4];
            r[i] += t.x * z.x + t.y * z.y + t.z * z.z + t.w * z.w;
        }
    }

    // ---- per-row diagonal: d_i = (1+eps) - Gamma_ii - lam_i ----
    float invd[N_DEP];
#pragma unroll
    for (int i = 0; i < N_DEP; i++)
        invd[i] = 1.0f / (1.0f + 1e-7f - sGd[i] - lam[i]);

    // ---- Jacobi: y_i <- (r_i + sum_{j!=i} Gamma_ij y_j) / d_i ----
    float y[N_DEP];
#pragma unroll
    for (int i = 0; i < N_DEP; i++) y[i] = r[i] * invd[i];   // first sweep from y0 = 0

    for (int it = 0; it < K_JACOBI - 1; ++it) {   // runtime loop; body fully unrolled
        float t[N_DEP];
#pragma unroll
        for (int i = 0; i < N_DEP; i++) {
            float s = r[i];
#pragma unroll
            for (int j4 = 0; j4 < N_DEP / 4; j4++) {
                float4 g = *(const float4*)&sG[i][j4 * 4];
                s += g.x * y[j4 * 4 + 0] + g.y * y[j4 * 4 + 1]
                   + g.z * y[j4 * 4 + 2] + g.w * y[j4 * 4 + 3];
            }
            t[i] = s * invd[i];
        }
#pragma unroll
        for (int i = 0; i < N_DEP; i++) y[i] = t[i];
    }

    // ---- store y (128 B contiguous per sample) ----
    float4* out = (float4*)(Yg + (blockBase + tid) * N_DEP);
#pragma unroll
    for (int i = 0; i < N_DEP / 4; i++)
        out[i] = make_float4(y[4 * i], y[4 * i + 1], y[4 * i + 2], y[4 * i + 3]);
}

extern "C" void kernel_launch(void* const* d_in, const int* in_sizes, int n_in,
                              void* d_out, int out_size, void* d_ws, size_t ws_size,
                              hipStream_t stream) {
    const float* X = (const float*)d_in[0];
    const float* Z = (const float*)d_in[1];
    const float* U = (const float*)d_in[2];
    const float* B = (const float*)d_in[3];
    const float* T = (const float*)d_in[4];
    const float* G = (const float*)d_in[5];
    const float* L = (const float*)d_in[6];
    float* Y = (float*)d_out;

    clefo_solve<<<dim3(BATCH / BLOCK), dim3(BLOCK), 0, stream>>>(X, Z, U, B, T, G, L, Y);
}

// Round 2
// 162.706 us; speedup vs baseline: 6.8000x; 6.8000x over previous
//
#include <hip/hip_runtime.h>

// Problem constants (from reference)
#define N_DEP    32
#define N_INDEP  64
#define N_INTER  16
#define BATCH    65536
#define NSWEEP   9       // Jacobi sweeps after the y0 = r/d init (10 total applications)
#define TPS      4       // threads per sample
#define ROWS     8       // rows per thread (N_DEP / TPS)
#define SPB      64      // samples per block
#define BLOCK    (SPB * TPS)   // 256 threads

// Design notes (R2):
//  - R1 spilled catastrophically (VGPR=256 cap, ~1.27 GB scratch traffic): 1 thread
//    held ~160 live floats. Now 4 threads/sample hold 8 rows each (~60 live floats).
//  - Cross-row y exchange per Jacobi sweep via __shfl_xor masks 1..3 (quad-local).
//  - All LDS tiles rotation-swizzled so the 4 distinct row-group addresses per
//    ds_read_b128 hit distinct bank groups; same-address lanes broadcast (free).
//  - __launch_bounds__(256,4) caps VGPRs at 128 -> 4 waves/SIMD allocator target.

__global__ __launch_bounds__(BLOCK, 4) void clefo_solve(
    const float* __restrict__ Xg, const float* __restrict__ Zg,
    const float* __restrict__ Ug, const float* __restrict__ Bg,
    const float* __restrict__ Tg, const float* __restrict__ Gg,
    const float* __restrict__ Lg, float* __restrict__ Yg)
{
    __shared__ __align__(16) float sB[N_DEP][N_INDEP];   // swizzle mask 15
    __shared__ __align__(16) float sL[N_DEP][N_INDEP];   // swizzle mask 15
    __shared__ __align__(16) float sT[N_DEP][N_INTER];   // swizzle mask 3
    __shared__ __align__(16) float sG[N_DEP][N_DEP];     // swizzle mask 7, diag zeroed
    __shared__ float sU[N_DEP];
    __shared__ float sGd[N_DEP];
    __shared__ __align__(16) float sX[SPB][N_INDEP];     // swizzle by sample, mask 15
    __shared__ __align__(16) float sZ[SPB][N_INTER];     // swizzle by sample, mask 3

    const int tid = threadIdx.x;
    const int sl  = tid >> 2;          // local sample index [0,64)
    const int q   = tid & 3;           // row-group (quarter) [0,4)
    const int row0 = q * ROWS;
    const size_t blockBase = (size_t)blockIdx.x * SPB;

    // ---- stage parameters (coalesced float4, row-group rotation swizzle) ----
    {
        const float4* Bv = (const float4*)Bg;
        const float4* Lv = (const float4*)Lg;
        for (int idx = tid; idx < N_DEP * (N_INDEP / 4); idx += BLOCK) {  // 512
            int r = idx >> 4, c = idx & 15;
            int dc = (c + (r >> 3)) & 15;
            *(float4*)&sB[r][dc * 4] = Bv[idx];
            *(float4*)&sL[r][dc * 4] = Lv[idx];
        }
        const float4* Gv = (const float4*)Gg;
        if (tid < N_DEP * (N_DEP / 4)) {                                  // 256
            int r = tid >> 3, c = tid & 7;
            float4 v = Gv[tid];
            if (c == (r >> 2)) {            // this chunk holds the diagonal element
                float* pv = (float*)&v;
                sGd[r] = pv[r & 3];
                pv[r & 3] = 0.0f;           // zero diag for off-diag matvec
            }
            int dc = (c + (r >> 3)) & 7;
            *(float4*)&sG[r][dc * 4] = v;
        }
        const float4* Tv = (const float4*)Tg;
        if (tid < N_DEP * (N_INTER / 4)) {                                // 128
            int r = tid >> 2, c = tid & 3;
            int dc = (c + (r >> 3)) & 3;
            *(float4*)&sT[r][dc * 4] = Tv[tid];
        }
        if (tid < N_DEP) sU[tid] = Ug[tid];
    }
    // ---- stage X/Z tiles (coalesced, per-sample rotation swizzle) ----
    {
        const float4* Xv = (const float4*)(Xg + blockBase * N_INDEP);
        for (int idx = tid; idx < SPB * (N_INDEP / 4); idx += BLOCK) {    // 1024
            float4 v = Xv[idx];
            int s = idx >> 4, c = idx & 15;
            *(float4*)&sX[s][((c + s) & 15) * 4] = v;
        }
        const float4* Zv = (const float4*)(Zg + blockBase * N_INTER);
        {
            int idx = tid;                                                // 256 exactly
            float4 v = Zv[idx];
            int s = idx >> 2, c = idx & 3;
            *(float4*)&sZ[s][((c + s) & 3) * 4] = v;
        }
    }
    __syncthreads();

    // ---- prologue: r = U + B x + T z ; lam = L x   (own 8 rows only) ----
    float r[ROWS], lam[ROWS];
#pragma unroll
    for (int i = 0; i < ROWS; i++) { r[i] = sU[row0 + i]; lam[i] = 0.0f; }

    for (int j4 = 0; j4 < N_INDEP / 4; j4++) {
        float4 x = *(const float4*)&sX[sl][((j4 + sl) & 15) * 4];
        const int bc = ((j4 + q) & 15) * 4;
#pragma unroll
        for (int i = 0; i < ROWS; i++) {
            float4 b = *(const float4*)&sB[row0 + i][bc];
            float4 l = *(const float4*)&sL[row0 + i][bc];
            r[i]   += b.x * x.x + b.y * x.y + b.z * x.z + b.w * x.w;
            lam[i] += l.x * x.x + l.y * x.y + l.z * x.z + l.w * x.w;
        }
    }
    for (int j4 = 0; j4 < N_INTER / 4; j4++) {
        float4 z = *(const float4*)&sZ[sl][((j4 + sl) & 3) * 4];
        const int tc = ((j4 + q) & 3) * 4;
#pragma unroll
        for (int i = 0; i < ROWS; i++) {
            float4 t = *(const float4*)&sT[row0 + i][tc];
            r[i] += t.x * z.x + t.y * z.y + t.z * z.z + t.w * z.w;
        }
    }

    // ---- diagonal: d_i = (1+reg) - Gamma_ii - lam_i ----
    float invd[ROWS], y[ROWS];
#pragma unroll
    for (int i = 0; i < ROWS; i++) {
        invd[i] = 1.0f / (1.0f + 1e-7f - sGd[row0 + i] - lam[i]);
        y[i] = r[i] * invd[i];          // first sweep from y0 = 0
    }

    // ---- Jacobi sweeps: y_i <- (r_i + sum_{j!=i} G_ij y_j) * invd_i ----
    for (int it = 0; it < NSWEEP; ++it) {
        float ys[TPS][ROWS];            // old y of all 4 row-groups (quad shuffle)
#pragma unroll
        for (int i = 0; i < ROWS; i++) {
            ys[0][i] = y[i];
            ys[1][i] = __shfl_xor(y[i], 1, 64);
            ys[2][i] = __shfl_xor(y[i], 2, 64);
            ys[3][i] = __shfl_xor(y[i], 3, 64);
        }
#pragma unroll
        for (int i = 0; i < ROWS; i++) {
            float s = r[i];
            const float* grow = &sG[row0 + i][0];
#pragma unroll
            for (int m = 0; m < TPS; m++) {       // partner row-group jq = q^m
#pragma unroll
                for (int c2 = 0; c2 < 2; c2++) {  // two float4 chunks of that group
                    const int sc = ((((q ^ m) << 1) + c2 + q) & 7) * 4;
                    float4 g = *(const float4*)&grow[sc];
                    s += g.x * ys[m][c2 * 4 + 0] + g.y * ys[m][c2 * 4 + 1]
                       + g.z * ys[m][c2 * 4 + 2] + g.w * ys[m][c2 * 4 + 3];
                }
            }
            y[i] = s * invd[i];         // safe in-place: sums read ys[], not y[]
        }
    }

    // ---- store own 8 contiguous outputs (quad covers 128 B contiguous) ----
    float4* out = (float4*)(Yg + (blockBase + sl) * N_DEP + row0);
    out[0] = make_float4(y[0], y[1], y[2], y[3]);
    out[1] = make_float4(y[4], y[5], y[6], y[7]);
}

extern "C" void kernel_launch(void* const* d_in, const int* in_sizes, int n_in,
                              void* d_out, int out_size, void* d_ws, size_t ws_size,
                              hipStream_t stream) {
    const float* X = (const float*)d_in[0];
    const float* Z = (const float*)d_in[1];
    const float* U = (const float*)d_in[2];
    const float* B = (const float*)d_in[3];
    const float* T = (const float*)d_in[4];
    const float* G = (const float*)d_in[5];
    const float* L = (const float*)d_in[6];
    float* Y = (float*)d_out;

    clefo_solve<<<dim3(BATCH / SPB), dim3(BLOCK), 0, stream>>>(X, Z, U, B, T, G, L, Y);
}

// Round 3
// 93.071 us; speedup vs baseline: 11.8877x; 1.7482x over previous
//
#include <hip/hip_runtime.h>
#include <stdint.h>

// Problem constants
#define N_DEP    32
#define N_INDEP  64
#define N_INTER  16
#define BATCH    65536
#define NSWEEP   9        // Jacobi MFMA sweeps after y0 = R*invd (10 applications total)
#define BLOCK    256      // 4 waves
#define SPB      64       // samples per block (4 waves x 16 samples/wave)

// R3 design: everything through mfma_f32_16x16x32_bf16, transposed form.
//   Per wave: 16 samples.  D[i][s] = sum_k A[i][k] B[k][s].
//   A-frags (params B, Lambda, Theta, Gamma_offdiag) wave-uniform, in registers.
//   B-frags = per-sample data (X, Z, then the y iterate).
//   C/D layout (verified): col = lane&15 (sample), row = (lane>>4)*4 + reg.
//   A layout   (verified): m = lane&15, k = (lane>>4)*8 + j.
//   B layout   (dual):     n = lane&15, k = (lane>>4)*8 + j.
//   Sweep: D = Gamma_off*Y + R (R as C operand), scale by invd, C->B via 8 shfl.
//   LDS used only for the final [row][sample] -> [sample][row] output transpose.

typedef __attribute__((ext_vector_type(8))) short short8;
typedef __attribute__((ext_vector_type(4))) float floatx4;

union FragU { short8 s; uint32_t u[4]; };

__device__ __forceinline__ uint32_t pk_bf16(float a, float b) {
    uint32_t ua = __builtin_bit_cast(uint32_t, a);
    uint32_t ub = __builtin_bit_cast(uint32_t, b);
    ua += 0x7FFFu + ((ua >> 16) & 1u);   // RNE
    ub += 0x7FFFu + ((ub >> 16) & 1u);
    return (ua >> 16) | (ub & 0xFFFF0000u);
}

__device__ __forceinline__ short8 pack8(const float* f) {
    FragU r;
    r.u[0] = pk_bf16(f[0], f[1]);
    r.u[1] = pk_bf16(f[2], f[3]);
    r.u[2] = pk_bf16(f[4], f[5]);
    r.u[3] = pk_bf16(f[6], f[7]);
    return r.s;
}

__global__ __launch_bounds__(BLOCK, 4) void clefo_mfma(
    const float* __restrict__ Xg, const float* __restrict__ Zg,
    const float* __restrict__ Ug, const float* __restrict__ Bg,
    const float* __restrict__ Tg, const float* __restrict__ Gg,
    const float* __restrict__ Lg, float* __restrict__ Yg)
{
    __shared__ float sY[SPB][36];   // 9216 B; +4 pad keeps 16B alignment for f4 reads

    const int lane = threadIdx.x & 63;
    const int wave = threadIdx.x >> 6;
    const int s    = lane & 15;      // B n-index / C col (sample)  OR  A m-index (row)
    const int h    = lane >> 4;      // quad
    const size_t samp = (size_t)blockIdx.x * SPB + wave * 16 + s;

    // ---- A-frag loader: row-major fp32 matrix M[32][ld], rows ro..ro+15, K-chunk k0 ----
    auto load_a = [&](const float* M, int ld, int ro, int kc) -> short8 {
        const int row = ro + s;
        const float* p = M + (size_t)row * ld + kc + h * 8;
        float4 a = *(const float4*)p;
        float4 b = *(const float4*)(p + 4);
        float t[8] = {a.x, a.y, a.z, a.w, b.x, b.y, b.z, b.w};
        return pack8(t);
    };
    // Gamma A-frag with diagonal zeroed (k = 8h+j covers full K=32)
    auto load_gamma = [&](int ro) -> short8 {
        const int row = ro + s;
        const float* p = Gg + (size_t)row * N_DEP + h * 8;
        float4 a = *(const float4*)p;
        float4 b = *(const float4*)(p + 4);
        float t[8] = {a.x, a.y, a.z, a.w, b.x, b.y, b.z, b.w};
        if ((row >> 3) == h) t[row & 7] = 0.0f;   // zero diag element
        return pack8(t);
    };
    // Theta A-frag: [32 x 16], zero-padded to K=32 (h>=2 all zero)
    auto load_theta = [&](int ro) -> short8 {
        float t[8] = {0,0,0,0,0,0,0,0};
        if (h < 2) {
            const float* p = Tg + (size_t)(ro + s) * N_INTER + h * 8;
            float4 a = *(const float4*)p;
            float4 b = *(const float4*)(p + 4);
            t[0]=a.x; t[1]=a.y; t[2]=a.z; t[3]=a.w;
            t[4]=b.x; t[5]=b.y; t[6]=b.z; t[7]=b.w;
        }
        return pack8(t);
    };

    // ---- B-frags: X (2 K-chunks) and Z (zero-padded) for this lane's sample ----
    short8 xf[2];
#pragma unroll
    for (int c = 0; c < 2; c++) {
        const float* p = Xg + samp * N_INDEP + c * 32 + h * 8;
        float4 a = *(const float4*)p;
        float4 b = *(const float4*)(p + 4);
        float t[8] = {a.x, a.y, a.z, a.w, b.x, b.y, b.z, b.w};
        xf[c] = pack8(t);
    }
    short8 zf;
    {
        float t[8] = {0,0,0,0,0,0,0,0};
        if (h < 2) {
            const float* p = Zg + samp * N_INTER + h * 8;
            float4 a = *(const float4*)p;
            float4 b = *(const float4*)(p + 4);
            t[0]=a.x; t[1]=a.y; t[2]=a.z; t[3]=a.w;
            t[4]=b.x; t[5]=b.y; t[6]=b.z; t[7]=b.w;
        }
        zf = pack8(t);
    }

    // ---- prologue GEMMs: R = U + B X^T + Theta Z^T ; lam = Lambda X^T ----
    floatx4 R1, R2, Lm1, Lm2;
#pragma unroll
    for (int r = 0; r < 4; r++) {
        R1[r] = Ug[4 * h + r];
        R2[r] = Ug[16 + 4 * h + r];
        Lm1[r] = 0.0f; Lm2[r] = 0.0f;
    }
    R1 = __builtin_amdgcn_mfma_f32_16x16x32_bf16(load_a(Bg, N_INDEP, 0,  0),  xf[0], R1, 0, 0, 0);
    R1 = __builtin_amdgcn_mfma_f32_16x16x32_bf16(load_a(Bg, N_INDEP, 0,  32), xf[1], R1, 0, 0, 0);
    R2 = __builtin_amdgcn_mfma_f32_16x16x32_bf16(load_a(Bg, N_INDEP, 16, 0),  xf[0], R2, 0, 0, 0);
    R2 = __builtin_amdgcn_mfma_f32_16x16x32_bf16(load_a(Bg, N_INDEP, 16, 32), xf[1], R2, 0, 0, 0);
    R1 = __builtin_amdgcn_mfma_f32_16x16x32_bf16(load_theta(0),  zf, R1, 0, 0, 0);
    R2 = __builtin_amdgcn_mfma_f32_16x16x32_bf16(load_theta(16), zf, R2, 0, 0, 0);
    Lm1 = __builtin_amdgcn_mfma_f32_16x16x32_bf16(load_a(Lg, N_INDEP, 0,  0),  xf[0], Lm1, 0, 0, 0);
    Lm1 = __builtin_amdgcn_mfma_f32_16x16x32_bf16(load_a(Lg, N_INDEP, 0,  32), xf[1], Lm1, 0, 0, 0);
    Lm2 = __builtin_amdgcn_mfma_f32_16x16x32_bf16(load_a(Lg, N_INDEP, 16, 0),  xf[0], Lm2, 0, 0, 0);
    Lm2 = __builtin_amdgcn_mfma_f32_16x16x32_bf16(load_a(Lg, N_INDEP, 16, 32), xf[1], Lm2, 0, 0, 0);

    // ---- Gamma_off frags: persist across all sweeps (registers, zero LDS) ----
    const short8 g1 = load_gamma(0);
    const short8 g2 = load_gamma(16);

    // ---- invd per owned (row, sample) cell ----
    float invd1[4], invd2[4], y1[4], y2[4];
#pragma unroll
    for (int r = 0; r < 4; r++) {
        const int i1 = 4 * h + r, i2 = 16 + 4 * h + r;
        invd1[r] = 1.0f / (1.0f + 1e-7f - Gg[i1 * 33] - Lm1[r]);
        invd2[r] = 1.0f / (1.0f + 1e-7f - Gg[i2 * 33] - Lm2[r]);
        y1[r] = R1[r] * invd1[r];    // y0 (first application, from y=0)
        y2[r] = R2[r] * invd2[r];
    }

    // ---- C-layout -> B-frag transform (in-register, 8 shfl + 4 selects) ----
    const int srcA = ((2 * h) & 3) * 16 + s;
    const int srcB = ((2 * h + 1) & 3) * 16 + s;
    const bool lo = (h < 2);
    auto c_to_b = [&]() -> short8 {
        uint32_t p0 = pk_bf16(y1[0], y1[1]), p1 = pk_bf16(y1[2], y1[3]);
        uint32_t p2 = pk_bf16(y2[0], y2[1]), p3 = pk_bf16(y2[2], y2[3]);
        uint32_t t0 = (uint32_t)__shfl((int)p0, srcA);
        uint32_t t1 = (uint32_t)__shfl((int)p1, srcA);
        uint32_t t2 = (uint32_t)__shfl((int)p2, srcA);
        uint32_t t3 = (uint32_t)__shfl((int)p3, srcA);
        uint32_t u0 = (uint32_t)__shfl((int)p0, srcB);
        uint32_t u1 = (uint32_t)__shfl((int)p1, srcB);
        uint32_t u2 = (uint32_t)__shfl((int)p2, srcB);
        uint32_t u3 = (uint32_t)__shfl((int)p3, srcB);
        FragU b;
        b.u[0] = lo ? t0 : t2;   // k pairs (8h+0, 8h+1)
        b.u[1] = lo ? t1 : t3;   // (8h+2, 8h+3)
        b.u[2] = lo ? u0 : u2;   // (8h+4, 8h+5)
        b.u[3] = lo ? u1 : u3;   // (8h+6, 8h+7)
        return b.s;
    };

    short8 yf = c_to_b();

    // ---- Jacobi sweeps: D = Gamma_off * Y + R, then scale by invd ----
    for (int it = 0; it < NSWEEP; ++it) {
        floatx4 D1 = __builtin_amdgcn_mfma_f32_16x16x32_bf16(g1, yf, R1, 0, 0, 0);
        floatx4 D2 = __builtin_amdgcn_mfma_f32_16x16x32_bf16(g2, yf, R2, 0, 0, 0);
#pragma unroll
        for (int r = 0; r < 4; r++) { y1[r] = D1[r] * invd1[r]; y2[r] = D2[r] * invd2[r]; }
        if (it < NSWEEP - 1) yf = c_to_b();
    }

    // ---- output transpose via LDS: [row][sample] -> [sample][row], coalesced store ----
    {
        const int sl = wave * 16 + s;
#pragma unroll
        for (int r = 0; r < 4; r++) {
            sY[sl][4 * h + r]      = y1[r];
            sY[sl][16 + 4 * h + r] = y2[r];
        }
    }
    __syncthreads();
    {
        const int t  = threadIdx.x;
        const int sl = t >> 2, q = t & 3;
        float4 v0 = *(const float4*)&sY[sl][q * 8];
        float4 v1 = *(const float4*)&sY[sl][q * 8 + 4];
        float4* op = (float4*)(Yg + ((size_t)blockIdx.x * SPB + sl) * N_DEP + q * 8);
        op[0] = v0;
        op[1] = v1;
    }
}

extern "C" void kernel_launch(void* const* d_in, const int* in_sizes, int n_in,
                              void* d_out, int out_size, void* d_ws, size_t ws_size,
                              hipStream_t stream) {
    const float* X = (const float*)d_in[0];
    const float* Z = (const float*)d_in[1];
    const float* U = (const float*)d_in[2];
    const float* B = (const float*)d_in[3];
    const float* T = (const float*)d_in[4];
    const float* G = (const float*)d_in[5];
    const float* L = (const float*)d_in[6];
    float* Y = (float*)d_out;

    clefo_mfma<<<dim3(BATCH / SPB), dim3(BLOCK), 0, stream>>>(X, Z, U, B, T, G, L, Y);
}

// Round 4
// 85.030 us; speedup vs baseline: 13.0118x; 1.0946x over previous
//
#include <hip/hip_runtime.h>
#include <stdint.h>

// Problem constants
#define N_DEP    32
#define N_INDEP  64
#define N_INTER  16
#define BATCH    65536
#define NSWEEP   5        // Jacobi MFMA sweeps after y0 = R*invd (6 applications total;
                          // contraction ~0.2/sweep -> conv err ~3e-5, under bf16 noise)
#define BLOCK    256      // 4 waves
#define SPB      64       // samples per block (4 waves x 16 samples/wave)

// R4 design (changes vs R3):
//  - A-frags (B, Lambda, Theta, Gamma_off) pre-packed ONCE per block into LDS:
//    wave w stages frags 3w..3w+2 (wave-uniform), then each lane ds_read_b128's
//    them. Removes ~24 redundant global loads + ~140 pack VALU per lane and
//    breaks the serial load->pack->MFMA prologue chain (kernel was latency-bound:
//    one batch of 4 waves/SIMD, no replacement waves).
//  - X/Z HBM loads issued first so ~900-cyc latency overlaps param staging.
//  - Frag ids: 0-3 = B (ro{0,16} x kc{0,32}), 4-7 = Lambda, 8-9 = Theta, 10-11 = Gamma.
//  MFMA layouts (HW-verified, unchanged from R3 which passed):
//    C/D: col = lane&15 (sample), row = (lane>>4)*4 + reg
//    A:   m = lane&15,  k = (lane>>4)*8 + j
//    B:   n = lane&15,  k = (lane>>4)*8 + j

typedef __attribute__((ext_vector_type(8))) short short8;
typedef __attribute__((ext_vector_type(4))) float floatx4;

union FragU { short8 s; uint32_t u[4]; uint4 v; };

__device__ __forceinline__ uint32_t pk_bf16(float a, float b) {
    uint32_t ua = __builtin_bit_cast(uint32_t, a);
    uint32_t ub = __builtin_bit_cast(uint32_t, b);
    ua += 0x7FFFu + ((ua >> 16) & 1u);   // RNE
    ub += 0x7FFFu + ((ub >> 16) & 1u);
    return (ua >> 16) | (ub & 0xFFFF0000u);
}

__device__ __forceinline__ short8 pack8(const float* f) {
    FragU r;
    r.u[0] = pk_bf16(f[0], f[1]);
    r.u[1] = pk_bf16(f[2], f[3]);
    r.u[2] = pk_bf16(f[4], f[5]);
    r.u[3] = pk_bf16(f[6], f[7]);
    return r.s;
}

__global__ __launch_bounds__(BLOCK, 4) void clefo_mfma(
    const float* __restrict__ Xg, const float* __restrict__ Zg,
    const float* __restrict__ Ug, const float* __restrict__ Bg,
    const float* __restrict__ Tg, const float* __restrict__ Gg,
    const float* __restrict__ Lg, float* __restrict__ Yg)
{
    __shared__ __align__(16) uint4  sA[12][64];   // 12 pre-packed A-frags, 12288 B
    __shared__ __align__(16) float  sY[SPB][36];  // output transpose, 9216 B

    const int lane = threadIdx.x & 63;
    const int wave = threadIdx.x >> 6;
    const int s    = lane & 15;      // B n-index (sample) / A m-index (row) / C col
    const int h    = lane >> 4;      // quad
    const size_t samp = (size_t)blockIdx.x * SPB + wave * 16 + s;

    // ---- 1) issue per-sample X/Z loads FIRST (HBM latency overlaps staging) ----
    float4 xr[2][2];
#pragma unroll
    for (int c = 0; c < 2; c++) {
        const float* p = Xg + samp * N_INDEP + c * 32 + h * 8;
        xr[c][0] = *(const float4*)p;
        xr[c][1] = *(const float4*)(p + 4);
    }
    float4 zr[2];
    if (h < 2) {
        const float* p = Zg + samp * N_INTER + h * 8;
        zr[0] = *(const float4*)p;
        zr[1] = *(const float4*)(p + 4);
    } else {
        zr[0] = make_float4(0, 0, 0, 0);
        zr[1] = make_float4(0, 0, 0, 0);
    }

    // ---- 2) stage pre-packed A-frags: wave w builds frags 3w .. 3w+2 ----
    {
        auto make_frag = [&](int f) -> short8 {
            if (f < 8) {                       // B (f<4) or Lambda (f>=4), [32x64]
                const float* M = (f < 4) ? Bg : Lg;
                const int ro = ((f >> 1) & 1) * 16;
                const int kc = (f & 1) * 32;
                const float* p = M + (size_t)(ro + s) * N_INDEP + kc + h * 8;
                float4 a = *(const float4*)p;
                float4 b = *(const float4*)(p + 4);
                float t[8] = {a.x, a.y, a.z, a.w, b.x, b.y, b.z, b.w};
                return pack8(t);
            } else if (f < 10) {               // Theta [32x16], zero-padded K
                float t[8] = {0, 0, 0, 0, 0, 0, 0, 0};
                if (h < 2) {
                    const float* p = Tg + (size_t)((f - 8) * 16 + s) * N_INTER + h * 8;
                    float4 a = *(const float4*)p;
                    float4 b = *(const float4*)(p + 4);
                    t[0] = a.x; t[1] = a.y; t[2] = a.z; t[3] = a.w;
                    t[4] = b.x; t[5] = b.y; t[6] = b.z; t[7] = b.w;
                }
                return pack8(t);
            } else {                           // Gamma [32x32], diagonal zeroed
                const int row = (f - 10) * 16 + s;
                const float* p = Gg + (size_t)row * N_DEP + h * 8;
                float4 a = *(const float4*)p;
                float4 b = *(const float4*)(p + 4);
                float t[8] = {a.x, a.y, a.z, a.w, b.x, b.y, b.z, b.w};
                if ((row >> 3) == h) t[row & 7] = 0.0f;
                return pack8(t);
            }
        };
#pragma unroll
        for (int i = 0; i < 3; i++) {          // f is wave-uniform -> no divergence
            const int f = wave * 3 + i;
            FragU u; u.s = make_frag(f);
            sA[f][lane] = u.v;
        }
    }
    __syncthreads();

    auto rd = [&](int f) -> short8 {
        FragU u; u.v = sA[f][lane];            // ds_read_b128, 2-way aliasing (free)
        return u.s;
    };

    // ---- 3) pack per-sample B-frags (X arrived during staging) ----
    short8 xf[2];
#pragma unroll
    for (int c = 0; c < 2; c++) {
        float t[8] = {xr[c][0].x, xr[c][0].y, xr[c][0].z, xr[c][0].w,
                      xr[c][1].x, xr[c][1].y, xr[c][1].z, xr[c][1].w};
        xf[c] = pack8(t);
    }
    short8 zf;
    {
        float t[8] = {zr[0].x, zr[0].y, zr[0].z, zr[0].w,
                      zr[1].x, zr[1].y, zr[1].z, zr[1].w};
        zf = pack8(t);
    }

    // ---- 4) prologue GEMMs: R = U + B X^T + Theta Z^T ; lam = Lambda X^T ----
    floatx4 R1, R2, Lm1, Lm2;
#pragma unroll
    for (int r = 0; r < 4; r++) {
        R1[r] = Ug[4 * h + r];
        R2[r] = Ug[16 + 4 * h + r];
        Lm1[r] = 0.0f; Lm2[r] = 0.0f;
    }
    R1  = __builtin_amdgcn_mfma_f32_16x16x32_bf16(rd(0),  xf[0], R1,  0, 0, 0);
    R1  = __builtin_amdgcn_mfma_f32_16x16x32_bf16(rd(1),  xf[1], R1,  0, 0, 0);
    R2  = __builtin_amdgcn_mfma_f32_16x16x32_bf16(rd(2),  xf[0], R2,  0, 0, 0);
    R2  = __builtin_amdgcn_mfma_f32_16x16x32_bf16(rd(3),  xf[1], R2,  0, 0, 0);
    R1  = __builtin_amdgcn_mfma_f32_16x16x32_bf16(rd(8),  zf,    R1,  0, 0, 0);
    R2  = __builtin_amdgcn_mfma_f32_16x16x32_bf16(rd(9),  zf,    R2,  0, 0, 0);
    Lm1 = __builtin_amdgcn_mfma_f32_16x16x32_bf16(rd(4),  xf[0], Lm1, 0, 0, 0);
    Lm1 = __builtin_amdgcn_mfma_f32_16x16x32_bf16(rd(5),  xf[1], Lm1, 0, 0, 0);
    Lm2 = __builtin_amdgcn_mfma_f32_16x16x32_bf16(rd(6),  xf[0], Lm2, 0, 0, 0);
    Lm2 = __builtin_amdgcn_mfma_f32_16x16x32_bf16(rd(7),  xf[1], Lm2, 0, 0, 0);

    // Gamma_off frags persist in registers across all sweeps
    const short8 g1 = rd(10);
    const short8 g2 = rd(11);

    // ---- 5) invd per owned (row, sample) cell; y0 = R * invd ----
    float invd1[4], invd2[4], y1[4], y2[4];
#pragma unroll
    for (int r = 0; r < 4; r++) {
        const int i1 = 4 * h + r, i2 = 16 + 4 * h + r;
        invd1[r] = 1.0f / (1.0f + 1e-7f - Gg[i1 * 33] - Lm1[r]);
        invd2[r] = 1.0f / (1.0f + 1e-7f - Gg[i2 * 33] - Lm2[r]);
        y1[r] = R1[r] * invd1[r];
        y2[r] = R2[r] * invd2[r];
    }

    // ---- C-layout -> B-frag transform (in-register: 8 shfl + 4 selects) ----
    const int srcA = ((2 * h) & 3) * 16 + s;
    const int srcB = ((2 * h + 1) & 3) * 16 + s;
    const bool lo = (h < 2);
    auto c_to_b = [&]() -> short8 {
        uint32_t p0 = pk_bf16(y1[0], y1[1]), p1 = pk_bf16(y1[2], y1[3]);
        uint32_t p2 = pk_bf16(y2[0], y2[1]), p3 = pk_bf16(y2[2], y2[3]);
        uint32_t t0 = (uint32_t)__shfl((int)p0, srcA);
        uint32_t t1 = (uint32_t)__shfl((int)p1, srcA);
        uint32_t t2 = (uint32_t)__shfl((int)p2, srcA);
        uint32_t t3 = (uint32_t)__shfl((int)p3, srcA);
        uint32_t u0 = (uint32_t)__shfl((int)p0, srcB);
        uint32_t u1 = (uint32_t)__shfl((int)p1, srcB);
        uint32_t u2 = (uint32_t)__shfl((int)p2, srcB);
        uint32_t u3 = (uint32_t)__shfl((int)p3, srcB);
        FragU b;
        b.u[0] = lo ? t0 : t2;
        b.u[1] = lo ? t1 : t3;
        b.u[2] = lo ? u0 : u2;
        b.u[3] = lo ? u1 : u3;
        return b.s;
    };

    short8 yf = c_to_b();

    // ---- 6) Jacobi sweeps: D = Gamma_off * Y + R, scale by invd ----
    for (int it = 0; it < NSWEEP; ++it) {
        floatx4 D1 = __builtin_amdgcn_mfma_f32_16x16x32_bf16(g1, yf, R1, 0, 0, 0);
        floatx4 D2 = __builtin_amdgcn_mfma_f32_16x16x32_bf16(g2, yf, R2, 0, 0, 0);
#pragma unroll
        for (int r = 0; r < 4; r++) { y1[r] = D1[r] * invd1[r]; y2[r] = D2[r] * invd2[r]; }
        if (it < NSWEEP - 1) yf = c_to_b();
    }

    // ---- 7) output transpose via LDS -> coalesced float4 stores ----
    {
        const int sl = wave * 16 + s;
#pragma unroll
        for (int r = 0; r < 4; r++) {
            sY[sl][4 * h + r]      = y1[r];
            sY[sl][16 + 4 * h + r] = y2[r];
        }
    }
    __syncthreads();
    {
        const int t  = threadIdx.x;
        const int sl = t >> 2, q = t & 3;
        float4 v0 = *(const float4*)&sY[sl][q * 8];
        float4 v1 = *(const float4*)&sY[sl][q * 8 + 4];
        float4* op = (float4*)(Yg + ((size_t)blockIdx.x * SPB + sl) * N_DEP + q * 8);
        op[0] = v0;
        op[1] = v1;
    }
}

extern "C" void kernel_launch(void* const* d_in, const int* in_sizes, int n_in,
                              void* d_out, int out_size, void* d_ws, size_t ws_size,
                              hipStream_t stream) {
    const float* X = (const float*)d_in[0];
    const float* Z = (const float*)d_in[1];
    const float* U = (const float*)d_in[2];
    const float* B = (const float*)d_in[3];
    const float* T = (const float*)d_in[4];
    const float* G = (const float*)d_in[5];
    const float* L = (const float*)d_in[6];
    float* Y = (float*)d_out;

    clefo_mfma<<<dim3(BATCH / SPB), dim3(BLOCK), 0, stream>>>(X, Z, U, B, T, G, L, Y);
}

// Round 5
// 84.469 us; speedup vs baseline: 13.0983x; 1.0066x over previous
//
#include <hip/hip_runtime.h>
#include <stdint.h>

// Problem constants
#define N_DEP    32
#define N_INDEP  64
#define N_INTER  16
#define BATCH    65536
#define NSWEEP   4        // Jacobi MFMA sweeps after y0 = R*invd (5 applications total;
                          // worst-case conv err ~7e-4 < observed bf16 noise 2e-3 << 1e-2 thr)
#define BLOCK    256      // 4 waves
#define SPB      64       // samples per block (4 waves x 16 samples/wave)

// R5 changes vs R4 (which passed at 85 us, absmax 1.95e-3):
//  - U and diag(Gamma) staged into LDS during the A-frag staging phase; invd/R
//    init now read wave-uniform LDS broadcasts instead of 16 scattered 4B
//    global loads per lane on the post-prologue critical path.
//  - NSWEEP 5 -> 4 (absmax is bf16-noise-dominated; R3 9-sweep == R4 5-sweep).
//  MFMA layouts (HW-verified across R3/R4 passes):
//    C/D: col = lane&15 (sample), row = (lane>>4)*4 + reg
//    A:   m = lane&15,  k = (lane>>4)*8 + j
//    B:   n = lane&15,  k = (lane>>4)*8 + j

typedef __attribute__((ext_vector_type(8))) short short8;
typedef __attribute__((ext_vector_type(4))) float floatx4;

union FragU { short8 s; uint32_t u[4]; uint4 v; };

__device__ __forceinline__ uint32_t pk_bf16(float a, float b) {
    uint32_t ua = __builtin_bit_cast(uint32_t, a);
    uint32_t ub = __builtin_bit_cast(uint32_t, b);
    ua += 0x7FFFu + ((ua >> 16) & 1u);   // RNE
    ub += 0x7FFFu + ((ub >> 16) & 1u);
    return (ua >> 16) | (ub & 0xFFFF0000u);
}

__device__ __forceinline__ short8 pack8(const float* f) {
    FragU r;
    r.u[0] = pk_bf16(f[0], f[1]);
    r.u[1] = pk_bf16(f[2], f[3]);
    r.u[2] = pk_bf16(f[4], f[5]);
    r.u[3] = pk_bf16(f[6], f[7]);
    return r.s;
}

__global__ __launch_bounds__(BLOCK, 4) void clefo_mfma(
    const float* __restrict__ Xg, const float* __restrict__ Zg,
    const float* __restrict__ Ug, const float* __restrict__ Bg,
    const float* __restrict__ Tg, const float* __restrict__ Gg,
    const float* __restrict__ Lg, float* __restrict__ Yg)
{
    __shared__ __align__(16) uint4  sA[12][64];   // 12 pre-packed A-frags, 12288 B
    __shared__ __align__(16) float  sY[SPB][36];  // output transpose, 9216 B
    __shared__ float sU[N_DEP];                   // Upsilon broadcast
    __shared__ float sGd[N_DEP];                  // diag(Gamma) broadcast

    const int lane = threadIdx.x & 63;
    const int wave = threadIdx.x >> 6;
    const int s    = lane & 15;      // B n-index (sample) / A m-index (row) / C col
    const int h    = lane >> 4;      // quad
    const size_t samp = (size_t)blockIdx.x * SPB + wave * 16 + s;

    // ---- 1) issue per-sample X/Z loads FIRST (HBM/L3 latency overlaps staging) ----
    float4 xr[2][2];
#pragma unroll
    for (int c = 0; c < 2; c++) {
        const float* p = Xg + samp * N_INDEP + c * 32 + h * 8;
        xr[c][0] = *(const float4*)p;
        xr[c][1] = *(const float4*)(p + 4);
    }
    float4 zr[2];
    if (h < 2) {
        const float* p = Zg + samp * N_INTER + h * 8;
        zr[0] = *(const float4*)p;
        zr[1] = *(const float4*)(p + 4);
    } else {
        zr[0] = make_float4(0, 0, 0, 0);
        zr[1] = make_float4(0, 0, 0, 0);
    }

    // ---- 2) stage U / diag(Gamma) (wave 3's first 32 lanes) + pre-packed A-frags ----
    if (wave == 3 && lane < N_DEP) {
        sU[lane]  = Ug[lane];
        sGd[lane] = Gg[lane * (N_DEP + 1)];
    }
    {
        auto make_frag = [&](int f) -> short8 {
            if (f < 8) {                       // B (f<4) or Lambda (f>=4), [32x64]
                const float* M = (f < 4) ? Bg : Lg;
                const int ro = ((f >> 1) & 1) * 16;
                const int kc = (f & 1) * 32;
                const float* p = M + (size_t)(ro + s) * N_INDEP + kc + h * 8;
                float4 a = *(const float4*)p;
                float4 b = *(const float4*)(p + 4);
                float t[8] = {a.x, a.y, a.z, a.w, b.x, b.y, b.z, b.w};
                return pack8(t);
            } else if (f < 10) {               // Theta [32x16], zero-padded K
                float t[8] = {0, 0, 0, 0, 0, 0, 0, 0};
                if (h < 2) {
                    const float* p = Tg + (size_t)((f - 8) * 16 + s) * N_INTER + h * 8;
                    float4 a = *(const float4*)p;
                    float4 b = *(const float4*)(p + 4);
                    t[0] = a.x; t[1] = a.y; t[2] = a.z; t[3] = a.w;
                    t[4] = b.x; t[5] = b.y; t[6] = b.z; t[7] = b.w;
                }
                return pack8(t);
            } else {                           // Gamma [32x32], diagonal zeroed
                const int row = (f - 10) * 16 + s;
                const float* p = Gg + (size_t)row * N_DEP + h * 8;
                float4 a = *(const float4*)p;
                float4 b = *(const float4*)(p + 4);
                float t[8] = {a.x, a.y, a.z, a.w, b.x, b.y, b.z, b.w};
                if ((row >> 3) == h) t[row & 7] = 0.0f;
                return pack8(t);
            }
        };
#pragma unroll
        for (int i = 0; i < 3; i++) {          // f is wave-uniform -> no divergence
            const int f = wave * 3 + i;
            FragU u; u.s = make_frag(f);
            sA[f][lane] = u.v;
        }
    }
    __syncthreads();

    auto rd = [&](int f) -> short8 {
        FragU u; u.v = sA[f][lane];            // ds_read_b128, 2-way aliasing (free)
        return u.s;
    };

    // ---- 3) pack per-sample B-frags (X arrived during staging) ----
    short8 xf[2];
#pragma unroll
    for (int c = 0; c < 2; c++) {
        float t[8] = {xr[c][0].x, xr[c][0].y, xr[c][0].z, xr[c][0].w,
                      xr[c][1].x, xr[c][1].y, xr[c][1].z, xr[c][1].w};
        xf[c] = pack8(t);
    }
    short8 zf;
    {
        float t[8] = {zr[0].x, zr[0].y, zr[0].z, zr[0].w,
                      zr[1].x, zr[1].y, zr[1].z, zr[1].w};
        zf = pack8(t);
    }

    // ---- 4) prologue GEMMs: R = U + B X^T + Theta Z^T ; lam = Lambda X^T ----
    floatx4 R1, R2, Lm1, Lm2;
#pragma unroll
    for (int r = 0; r < 4; r++) {
        R1[r] = sU[4 * h + r];                 // LDS broadcast (free)
        R2[r] = sU[16 + 4 * h + r];
        Lm1[r] = 0.0f; Lm2[r] = 0.0f;
    }
    R1  = __builtin_amdgcn_mfma_f32_16x16x32_bf16(rd(0),  xf[0], R1,  0, 0, 0);
    R1  = __builtin_amdgcn_mfma_f32_16x16x32_bf16(rd(1),  xf[1], R1,  0, 0, 0);
    R2  = __builtin_amdgcn_mfma_f32_16x16x32_bf16(rd(2),  xf[0], R2,  0, 0, 0);
    R2  = __builtin_amdgcn_mfma_f32_16x16x32_bf16(rd(3),  xf[1], R2,  0, 0, 0);
    R1  = __builtin_amdgcn_mfma_f32_16x16x32_bf16(rd(8),  zf,    R1,  0, 0, 0);
    R2  = __builtin_amdgcn_mfma_f32_16x16x32_bf16(rd(9),  zf,    R2,  0, 0, 0);
    Lm1 = __builtin_amdgcn_mfma_f32_16x16x32_bf16(rd(4),  xf[0], Lm1, 0, 0, 0);
    Lm1 = __builtin_amdgcn_mfma_f32_16x16x32_bf16(rd(5),  xf[1], Lm1, 0, 0, 0);
    Lm2 = __builtin_amdgcn_mfma_f32_16x16x32_bf16(rd(6),  xf[0], Lm2, 0, 0, 0);
    Lm2 = __builtin_amdgcn_mfma_f32_16x16x32_bf16(rd(7),  xf[1], Lm2, 0, 0, 0);

    // Gamma_off frags persist in registers across all sweeps
    const short8 g1 = rd(10);
    const short8 g2 = rd(11);

    // ---- 5) invd per owned (row, sample) cell; y0 = R * invd ----
    float invd1[4], invd2[4], y1[4], y2[4];
#pragma unroll
    for (int r = 0; r < 4; r++) {
        const int i1 = 4 * h + r, i2 = 16 + 4 * h + r;
        invd1[r] = 1.0f / (1.0f + 1e-7f - sGd[i1] - Lm1[r]);   // LDS broadcast
        invd2[r] = 1.0f / (1.0f + 1e-7f - sGd[i2] - Lm2[r]);
        y1[r] = R1[r] * invd1[r];
        y2[r] = R2[r] * invd2[r];
    }

    // ---- C-layout -> B-frag transform (in-register: 8 shfl + 4 selects) ----
    const int srcA = ((2 * h) & 3) * 16 + s;
    const int srcB = ((2 * h + 1) & 3) * 16 + s;
    const bool lo = (h < 2);
    auto c_to_b = [&]() -> short8 {
        uint32_t p0 = pk_bf16(y1[0], y1[1]), p1 = pk_bf16(y1[2], y1[3]);
        uint32_t p2 = pk_bf16(y2[0], y2[1]), p3 = pk_bf16(y2[2], y2[3]);
        uint32_t t0 = (uint32_t)__shfl((int)p0, srcA);
        uint32_t t1 = (uint32_t)__shfl((int)p1, srcA);
        uint32_t t2 = (uint32_t)__shfl((int)p2, srcA);
        uint32_t t3 = (uint32_t)__shfl((int)p3, srcA);
        uint32_t u0 = (uint32_t)__shfl((int)p0, srcB);
        uint32_t u1 = (uint32_t)__shfl((int)p1, srcB);
        uint32_t u2 = (uint32_t)__shfl((int)p2, srcB);
        uint32_t u3 = (uint32_t)__shfl((int)p3, srcB);
        FragU b;
        b.u[0] = lo ? t0 : t2;
        b.u[1] = lo ? t1 : t3;
        b.u[2] = lo ? u0 : u2;
        b.u[3] = lo ? u1 : u3;
        return b.s;
    };

    short8 yf = c_to_b();

    // ---- 6) Jacobi sweeps: D = Gamma_off * Y + R, scale by invd ----
    for (int it = 0; it < NSWEEP; ++it) {
        floatx4 D1 = __builtin_amdgcn_mfma_f32_16x16x32_bf16(g1, yf, R1, 0, 0, 0);
        floatx4 D2 = __builtin_amdgcn_mfma_f32_16x16x32_bf16(g2, yf, R2, 0, 0, 0);
#pragma unroll
        for (int r = 0; r < 4; r++) { y1[r] = D1[r] * invd1[r]; y2[r] = D2[r] * invd2[r]; }
        if (it < NSWEEP - 1) yf = c_to_b();
    }

    // ---- 7) output transpose via LDS -> coalesced float4 stores ----
    {
        const int sl = wave * 16 + s;
#pragma unroll
        for (int r = 0; r < 4; r++) {
            sY[sl][4 * h + r]      = y1[r];
            sY[sl][16 + 4 * h + r] = y2[r];
        }
    }
    __syncthreads();
    {
        const int t  = threadIdx.x;
        const int sl = t >> 2, q = t & 3;
        float4 v0 = *(const float4*)&sY[sl][q * 8];
        float4 v1 = *(const float4*)&sY[sl][q * 8 + 4];
        float4* op = (float4*)(Yg + ((size_t)blockIdx.x * SPB + sl) * N_DEP + q * 8);
        op[0] = v0;
        op[1] = v1;
    }
}

extern "C" void kernel_launch(void* const* d_in, const int* in_sizes, int n_in,
                              void* d_out, int out_size, void* d_ws, size_t ws_size,
                              hipStream_t stream) {
    const float* X = (const float*)d_in[0];
    const float* Z = (const float*)d_in[1];
    const float* U = (const float*)d_in[2];
    const float* B = (const float*)d_in[3];
    const float* T = (const float*)d_in[4];
    const float* G = (const float*)d_in[5];
    const float* L = (const float*)d_in[6];
    float* Y = (float*)d_out;

    clefo_mfma<<<dim3(BATCH / SPB), dim3(BLOCK), 0, stream>>>(X, Z, U, B, T, G, L, Y);
}